// Round 15
// baseline (80.842 us; speedup 1.0000x reference)
//
#include <hip/hip_runtime.h>
#include <hip/hip_bf16.h>
#include <math.h>

typedef __bf16 bf16;
typedef __attribute__((ext_vector_type(4))) float f32x4;
typedef __attribute__((ext_vector_type(4))) bf16 bf16x4;
typedef __attribute__((ext_vector_type(8))) bf16 bf16x8;

#define M_TOT 16384
#define K_TOT 1024
#define D_EMB 512
#define NT 32          // K tiles of 32

// ============================================================
// Pass 0 (unchanged, verified r9-r14): W -> fragment-ordered bf16
// image (2 MB). Blob (es, kt) = 1 KB:
//   img[es*16384 + kt*512 + l*8 + j]
//     = W_cat[es*16 + (l&15)][kt*32 + (l>>4)*8 + j]
// ============================================================
__global__ __launch_bounds__(256) void cvt_w_img(
    const float* __restrict__ W_mu, const float* __restrict__ W_logvar,
    bf16* __restrict__ img)
{
    const int c  = blockIdx.x * 256 + threadIdx.x;   // 0..131071
    const int l  = c & 63;
    const int kt = (c >> 6) & 31;
    const int es = c >> 11;                          // 0..63
    const int col = es * 16 + (l & 15);
    const int k0  = kt * 32 + (l >> 4) * 8;
    const float* s = (col < D_EMB) ? (W_mu + (size_t)col * K_TOT + k0)
                                   : (W_logvar + (size_t)(col - D_EMB) * K_TOT + k0);
    f32x4 a = ((const f32x4*)s)[0];
    f32x4 b = ((const f32x4*)s)[1];
    bf16x8 o;
    o[0] = (bf16)a[0]; o[1] = (bf16)a[1]; o[2] = (bf16)a[2]; o[3] = (bf16)a[3];
    o[4] = (bf16)b[0]; o[5] = (bf16)b[1]; o[6] = (bf16)b[2]; o[7] = (bf16)b[3];
    *(bf16x8*)(img + (size_t)c * 8) = o;
}

// ============================================================
// Tall-skinny, whole-K-in-LDS, 16 WAVES (4/SIMD TLP experiment).
// Block = 64 rows x 1024 cols, grid 256 (x read exactly once).
// 1024 threads = 16 waves; per phase each wave owns 64 rows x 32
// cols (acc[4][2]). Phase 1 = logvar (expf stores overlap phase-2
// compute), phase 2 = mu (cheap tail stores).
//   A staging: 4 chunks of K=256; gload(c+1) in flight during
//     chunk-c compute; vmcnt(4) per chunk (4 youngest = last 2
//     tiles' B prefetch); chunk LDS regions write-disjoint -> the
//     per-chunk barrier is visibility-only, no WAR.
//   A swizzle (verified r13/r14): row slot s stored at s^(row&7);
//     reads XOR by fr&7 (row&7 == fr&7 for row = m*16+fr).
//   B: global->VGPR from fragment image, 2-tile ping-pong.
// ============================================================
__global__ __launch_bounds__(1024, 1) void gpe_tall4(
    const float* __restrict__ x,
    const bf16* __restrict__ wimg,
    const float* __restrict__ b_mu,
    const float* __restrict__ b_logvar,
    float* __restrict__ out)         // [2][16384][512]
{
    __shared__ __align__(16) bf16 Alds[64 * 1024];   // 128 KB

    const int tid  = threadIdx.x;
    const int lane = tid & 63;
    const int w    = tid >> 6;        // 0..15
    const int fr   = lane & 15;
    const int g16  = lane >> 4;       // 0..3
    const int frx  = fr & 7;
    const int bm   = blockIdx.x;      // 0..255

    // ---- staging geometry: thread owns 16 f32 of one row per chunk ----
    const int arow = tid >> 4;                        // 0..63
    const int si   = tid & 15;
    const int rx   = arow & 7;
    const float* __restrict__ Asrc = x + (size_t)(bm * 64 + arow) * K_TOT;

    f32x4 stg[4];
    auto gload = [&](int c) {
#pragma unroll
        for (int j = 0; j < 4; ++j)
            stg[j] = *(const f32x4*)(Asrc + c * 256 + si * 16 + j * 4);
    };
    auto cvtwrite = [&](int c) {
#pragma unroll
        for (int h = 0; h < 2; ++h) {
            bf16x8 wv;
#pragma unroll
            for (int q = 0; q < 4; ++q) {
                wv[q]     = (bf16)stg[2 * h][q];
                wv[q + 4] = (bf16)stg[2 * h + 1][q];
            }
            const int slot = c * 32 + si * 2 + h;
            *(bf16x8*)&Alds[arow * 1024 + (slot ^ rx) * 8] = wv;
        }
    };

    // ---- B: 2 estrips per wave per phase ----
    const bf16* __restrict__ bl = wimg + lane * 8;
    bf16x8 bvA[2], bvB[2];
    auto loadB = [&](size_t e0, int t, bf16x8 (&bv)[2]) {
#pragma unroll
        for (int ns = 0; ns < 2; ++ns)
            bv[ns] = *(const bf16x8*)(bl + e0 + (size_t)ns * 16384 + t * 512);
    };

    f32x4 acc[4][2];
#pragma unroll
    for (int m = 0; m < 4; ++m)
#pragma unroll
        for (int n = 0; n < 2; ++n)
            acc[m][n] = (f32x4){0.f, 0.f, 0.f, 0.f};

    const size_t e0p0 = (size_t)(32 + w * 2) * 16384;   // phase 1: logvar
    const size_t e0p1 = (size_t)(w * 2) * 16384;        // phase 2: mu

#define TILE_BODY(T, E0, BVC)                                                  \
    {                                                                          \
        const int t = (T);                                                     \
        bf16x8 afc[4];                                                         \
        _Pragma("unroll")                                                      \
        for (int m = 0; m < 4; ++m)                                            \
            afc[m] = *(const bf16x8*)&Alds[(m * 16 + fr) * 1024                \
                                           + ((t * 4 + g16) ^ frx) * 8];       \
        __builtin_amdgcn_s_setprio(1);                                         \
        _Pragma("unroll")                                                      \
        for (int ns = 0; ns < 2; ++ns)                                         \
            _Pragma("unroll")                                                  \
            for (int m = 0; m < 4; ++m)                                        \
                acc[m][ns] = __builtin_amdgcn_mfma_f32_16x16x32_bf16(          \
                    afc[m], BVC[ns], acc[m][ns], 0, 0, 0);                     \
        __builtin_amdgcn_s_setprio(0);                                         \
        if (t + 2 < NT) loadB(E0, t + 2, BVC);                                 \
    }

    // ================= phase 1: logvar + chunked staging =================
    gload(0);
    for (int c = 0; c < 4; ++c) {
        if (c == 0) asm volatile("s_waitcnt vmcnt(0)" ::: "memory");
        else        asm volatile("s_waitcnt vmcnt(4)" ::: "memory");
        cvtwrite(c);
        if (c < 3) gload(c + 1);
        if (c == 0) { loadB(e0p0, 0, bvA); loadB(e0p0, 1, bvB); }
        asm volatile("s_waitcnt lgkmcnt(0)" ::: "memory");
        __builtin_amdgcn_s_barrier();
#pragma unroll
        for (int tt = 0; tt < 8; tt += 2) {
            TILE_BODY(c * 8 + tt,     e0p0, bvA)
            TILE_BODY(c * 8 + tt + 1, e0p0, bvB)
        }
    }

    // phase-2 B prologue first, then logvar stores (drain under phase 2)
    loadB(e0p1, 0, bvA);
    loadB(e0p1, 1, bvB);
    {
        float* __restrict__ obase = out + (size_t)M_TOT * D_EMB;   // logvar
#pragma unroll
        for (int m = 0; m < 4; ++m) {
            const int row0 = bm * 64 + m * 16 + g16 * 4;
#pragma unroll
            for (int ns = 0; ns < 2; ++ns) {
                const int cl = w * 32 + ns * 16 + fr;
                const float bvs = b_logvar[cl];
#pragma unroll
                for (int j = 0; j < 4; ++j)
                    obase[(size_t)(row0 + j) * D_EMB + cl] =
                        __expf(0.5f * (acc[m][ns][j] + bvs));
            }
        }
    }

    // ================= phase 2: mu, pure compute =================
#pragma unroll
    for (int m = 0; m < 4; ++m)
#pragma unroll
        for (int n = 0; n < 2; ++n)
            acc[m][n] = (f32x4){0.f, 0.f, 0.f, 0.f};

#pragma unroll
    for (int tt = 0; tt < NT; tt += 2) {
        TILE_BODY(tt,     e0p1, bvA)
        TILE_BODY(tt + 1, e0p1, bvB)
    }
#undef TILE_BODY

    {
        float* __restrict__ obase = out;              // mu
#pragma unroll
        for (int m = 0; m < 4; ++m) {
            const int row0 = bm * 64 + m * 16 + g16 * 4;
#pragma unroll
            for (int ns = 0; ns < 2; ++ns) {
                const int cl = w * 32 + ns * 16 + fr;
                const float bvs = b_mu[cl];
#pragma unroll
                for (int j = 0; j < 4; ++j)
                    obase[(size_t)(row0 + j) * D_EMB + cl] = acc[m][ns][j] + bvs;
            }
        }
    }
}

// ============================================================
// Fallback (no workspace): round-1 f32-staging GEMM
// ============================================================
#define LDS_STRIDE 40
__global__ __launch_bounds__(256) void gpe_gemm_fb(
    const float* __restrict__ x, const float* __restrict__ W_mu,
    const float* __restrict__ b_mu, const float* __restrict__ W_logvar,
    const float* __restrict__ b_logvar, float* __restrict__ out)
{
    __shared__ __align__(16) bf16 As[128][LDS_STRIDE];
    __shared__ __align__(16) bf16 Bs[128][LDS_STRIDE];
    const int tid = threadIdx.x, lane = tid & 63, wid = tid >> 6;
    const int wr = wid >> 1, wcn = wid & 1;
    const int bn = blockIdx.x & 7, bm = blockIdx.x >> 3;
    const int ebase = bn * 128;
    const bool is_mu = (ebase < D_EMB);
    const float* Wp = is_mu ? (W_mu + (size_t)ebase * K_TOT)
                            : (W_logvar + (size_t)(ebase - D_EMB) * K_TOT);
    const float* bias = is_mu ? b_mu : b_logvar;
    const int cbase = is_mu ? ebase : (ebase - D_EMB);
    float* obase = is_mu ? out : (out + (size_t)M_TOT * D_EMB);
    const float* Ap = x + (size_t)(bm * 128) * K_TOT;
    f32x4 acc[4][4];
#pragma unroll
    for (int m = 0; m < 4; ++m)
#pragma unroll
        for (int n = 0; n < 4; ++n) acc[m][n] = (f32x4){0.f, 0.f, 0.f, 0.f};
    const int fr = lane & 15, fk = (lane >> 4) * 8;
    const int arow = wr * 64 + fr, brow = wcn * 64 + fr;
    for (int kt = 0; kt < K_TOT / 32; ++kt) {
        const int k0 = kt * 32;
#pragma unroll
        for (int s = 0; s < 4; ++s) {
            const int idx = s * 256 + tid;
            const int row = idx >> 3, col = (idx & 7) << 2;
            f32x4 va = *reinterpret_cast<const f32x4*>(Ap + (size_t)row * K_TOT + k0 + col);
            f32x4 vb = *reinterpret_cast<const f32x4*>(Wp + (size_t)row * K_TOT + k0 + col);
            bf16x4 ha, hb;
#pragma unroll
            for (int j = 0; j < 4; ++j) { ha[j] = (bf16)va[j]; hb[j] = (bf16)vb[j]; }
            *reinterpret_cast<bf16x4*>(&As[row][col]) = ha;
            *reinterpret_cast<bf16x4*>(&Bs[row][col]) = hb;
        }
        __syncthreads();
        bf16x8 af[4], bfv[4];
#pragma unroll
        for (int m = 0; m < 4; ++m)
            af[m] = *reinterpret_cast<const bf16x8*>(&As[arow + m * 16][fk]);
#pragma unroll
        for (int n = 0; n < 4; ++n)
            bfv[n] = *reinterpret_cast<const bf16x8*>(&Bs[brow + n * 16][fk]);
#pragma unroll
        for (int m = 0; m < 4; ++m)
#pragma unroll
            for (int n = 0; n < 4; ++n)
                acc[m][n] = __builtin_amdgcn_mfma_f32_16x16x32_bf16(af[m], bfv[n], acc[m][n], 0, 0, 0);
        __syncthreads();
    }
#pragma unroll
    for (int m = 0; m < 4; ++m) {
        const int rbase = bm * 128 + wr * 64 + m * 16 + (lane >> 4) * 4;
#pragma unroll
        for (int n = 0; n < 4; ++n) {
            const int c = cbase + wcn * 64 + n * 16 + (lane & 15);
            const float bv = bias[c];
#pragma unroll
            for (int j = 0; j < 4; ++j) {
                float v = acc[m][n][j] + bv;
                if (!is_mu) v = __expf(0.5f * v);
                obase[(size_t)(rbase + j) * D_EMB + c] = v;
            }
        }
    }
}

extern "C" void kernel_launch(void* const* d_in, const int* in_sizes, int n_in,
                              void* d_out, int out_size, void* d_ws, size_t ws_size,
                              hipStream_t stream) {
    const float* x        = (const float*)d_in[0];
    const float* W_mu     = (const float*)d_in[1];
    const float* b_mu     = (const float*)d_in[2];
    const float* W_logvar = (const float*)d_in[3];
    const float* b_logvar = (const float*)d_in[4];
    float* out = (float*)d_out;

    const size_t ws_needed = (size_t)1024 * 1024 * sizeof(bf16);   // 2 MB W image

    if (ws_size >= ws_needed) {
        bf16* wimg = (bf16*)d_ws;
        cvt_w_img<<<512, 256, 0, stream>>>(W_mu, W_logvar, wimg);
        gpe_tall4<<<256, 1024, 0, stream>>>(x, wimg, b_mu, b_logvar, out);
    } else {
        gpe_gemm_fb<<<1024, 256, 0, stream>>>(x, W_mu, b_mu, W_logvar, b_logvar, out);
    }
}

// Round 16
// 57.948 us; speedup vs baseline: 1.3951x; 1.3951x over previous
//
#include <hip/hip_runtime.h>
#include <hip/hip_bf16.h>
#include <math.h>

typedef __bf16 bf16;
typedef __attribute__((ext_vector_type(4))) float f32x4;
typedef __attribute__((ext_vector_type(4))) bf16 bf16x4;
typedef __attribute__((ext_vector_type(8))) bf16 bf16x8;

#define M_TOT 16384
#define K_TOT 1024
#define D_EMB 512
#define NT 32          // K tiles of 32

// ============================================================
// Pass 0 (unchanged, verified r9-r15): W -> fragment-ordered bf16
// image (2 MB). Blob (es, kt) = 1 KB:
//   img[es*16384 + kt*512 + l*8 + j]
//     = W_cat[es*16 + (l&15)][kt*32 + (l>>4)*8 + j]
// ============================================================
__global__ __launch_bounds__(256) void cvt_w_img(
    const float* __restrict__ W_mu, const float* __restrict__ W_logvar,
    bf16* __restrict__ img)
{
    const int c  = blockIdx.x * 256 + threadIdx.x;   // 0..131071
    const int l  = c & 63;
    const int kt = (c >> 6) & 31;
    const int es = c >> 11;                          // 0..63
    const int col = es * 16 + (l & 15);
    const int k0  = kt * 32 + (l >> 4) * 8;
    const float* s = (col < D_EMB) ? (W_mu + (size_t)col * K_TOT + k0)
                                   : (W_logvar + (size_t)(col - D_EMB) * K_TOT + k0);
    f32x4 a = ((const f32x4*)s)[0];
    f32x4 b = ((const f32x4*)s)[1];
    bf16x8 o;
    o[0] = (bf16)a[0]; o[1] = (bf16)a[1]; o[2] = (bf16)a[2]; o[3] = (bf16)a[3];
    o[4] = (bf16)b[0]; o[5] = (bf16)b[1]; o[6] = (bf16)b[2]; o[7] = (bf16)b[3];
    *(bf16x8*)(img + (size_t)c * 8) = o;
}

// ============================================================
// Tall-skinny, whole-K-in-LDS (r14 structure, micro-tuned):
// Block = 64 rows x 1024 cols, grid 256 (x read exactly once).
// 8 waves; per phase each wave owns 64 rows x 64 cols (acc[4][4],
// 256B/row store footprint -> full-granularity HBM writes, r15 lesson).
//   Phase 1 = LOGVAR + chunked staging (4 chunks of K=256, gload(c+1)
//     in flight under chunk-c compute; vmcnt(16) safety at chunk entry;
//     one visibility barrier per chunk, write-disjoint regions).
//   Phase-1 expf store burst drains UNDER phase-2 compute.
//   Phase 2 = MU over the same resident LDS, zero barriers.
//   B: global->VGPR from fragment image, 4-DEEP ring (bv0..bv3).
// A swizzle (verified r13/r14): slot s stored at s^(row&7); reads
// XOR by fr&7. Benign ~4cyc/b128 2-lane aliasing only.
// ============================================================
__global__ __launch_bounds__(512, 1) void gpe_tall5(
    const float* __restrict__ x,
    const bf16* __restrict__ wimg,
    const float* __restrict__ b_mu,
    const float* __restrict__ b_logvar,
    float* __restrict__ out)         // [2][16384][512]
{
    __shared__ __align__(16) bf16 Alds[64 * 1024];   // 128 KB

    const int tid  = threadIdx.x;
    const int lane = tid & 63;
    const int wc   = tid >> 6;        // 0..7 : 64-col band within half
    const int fr   = lane & 15;
    const int g16  = lane >> 4;       // 0..3
    const int frx  = fr & 7;
    const int bm   = blockIdx.x;      // 0..255

    // ---- staging geometry (r14-verified) ----
    const int arow = tid >> 3;                        // 0..63
    const int sl0  = tid & 7;
    const int rx   = arow & 7;
    const float* __restrict__ Asrc = x + (size_t)(bm * 64 + arow) * K_TOT;

    f32x4 stg[8];
    auto gload = [&](int c) {
#pragma unroll
        for (int j = 0; j < 4; ++j) {
            const int s = c * 32 + sl0 + 8 * j;
            stg[2 * j]     = *(const f32x4*)(Asrc + s * 8);
            stg[2 * j + 1] = *(const f32x4*)(Asrc + s * 8 + 4);
        }
    };
    auto cvtwrite = [&](int c) {
#pragma unroll
        for (int j = 0; j < 4; ++j) {
            const int s = c * 32 + sl0 + 8 * j;
            bf16x8 w;
#pragma unroll
            for (int q = 0; q < 4; ++q) {
                w[q]     = (bf16)stg[2 * j][q];
                w[q + 4] = (bf16)stg[2 * j + 1][q];
            }
            *(bf16x8*)&Alds[arow * 1024 + (s ^ rx) * 8] = w;
        }
    };

    // ---- B: 4 estrips per wave per phase, 4-deep ring ----
    const bf16* __restrict__ bl = wimg + lane * 8;
    bf16x8 bv0[4], bv1[4], bv2[4], bv3[4];
    auto loadB = [&](size_t e0, int t, bf16x8 (&bv)[4]) {
#pragma unroll
        for (int ns = 0; ns < 4; ++ns)
            bv[ns] = *(const bf16x8*)(bl + e0 + (size_t)ns * 16384 + t * 512);
    };

    f32x4 acc[4][4];
#pragma unroll
    for (int m = 0; m < 4; ++m)
#pragma unroll
        for (int n = 0; n < 4; ++n)
            acc[m][n] = (f32x4){0.f, 0.f, 0.f, 0.f};

    const size_t e0p0 = (size_t)(32 + wc * 4) * 16384;   // phase 1: logvar
    const size_t e0p1 = (size_t)(wc * 4) * 16384;        // phase 2: mu

#define TILE_BODY(T, E0, BVC)                                                  \
    {                                                                          \
        const int t = (T);                                                     \
        bf16x8 afc[4];                                                         \
        _Pragma("unroll")                                                      \
        for (int m = 0; m < 4; ++m)                                            \
            afc[m] = *(const bf16x8*)&Alds[(m * 16 + fr) * 1024                \
                                           + ((t * 4 + g16) ^ frx) * 8];       \
        __builtin_amdgcn_s_setprio(1);                                         \
        _Pragma("unroll")                                                      \
        for (int ns = 0; ns < 4; ++ns)                                         \
            _Pragma("unroll")                                                  \
            for (int m = 0; m < 4; ++m)                                        \
                acc[m][ns] = __builtin_amdgcn_mfma_f32_16x16x32_bf16(          \
                    afc[m], BVC[ns], acc[m][ns], 0, 0, 0);                     \
        __builtin_amdgcn_s_setprio(0);                                         \
        if (t + 4 < NT) loadB(E0, t + 4, BVC);   /* refill just-consumed */    \
    }

    // ================= phase 1: logvar + chunked staging =================
    gload(0);
    for (int c = 0; c < 4; ++c) {
        if (c == 0) asm volatile("s_waitcnt vmcnt(0)" ::: "memory");
        else        asm volatile("s_waitcnt vmcnt(16)" ::: "memory");  // safety; B-waits already drained gload(c)
        cvtwrite(c);
        if (c < 3) gload(c + 1);
        if (c == 0) {
            loadB(e0p0, 0, bv0); loadB(e0p0, 1, bv1);
            loadB(e0p0, 2, bv2); loadB(e0p0, 3, bv3);
        }
        asm volatile("s_waitcnt lgkmcnt(0)" ::: "memory");
        __builtin_amdgcn_s_barrier();
#pragma unroll
        for (int tt = 0; tt < 8; tt += 4) {
            TILE_BODY(c * 8 + tt,     e0p0, bv0)
            TILE_BODY(c * 8 + tt + 1, e0p0, bv1)
            TILE_BODY(c * 8 + tt + 2, e0p0, bv2)
            TILE_BODY(c * 8 + tt + 3, e0p0, bv3)
        }
    }

    // phase-2 B prologue FIRST (gets L2 loads moving), then logvar stores
    // (33 MB expf burst drains under phase-2 compute)
    loadB(e0p1, 0, bv0); loadB(e0p1, 1, bv1);
    loadB(e0p1, 2, bv2); loadB(e0p1, 3, bv3);
    {
        float* __restrict__ obase = out + (size_t)M_TOT * D_EMB;   // logvar
#pragma unroll
        for (int m = 0; m < 4; ++m) {
            const int row0 = bm * 64 + m * 16 + g16 * 4;
#pragma unroll
            for (int ns = 0; ns < 4; ++ns) {
                const int cl = wc * 64 + ns * 16 + fr;
                const float bvs = b_logvar[cl];
#pragma unroll
                for (int j = 0; j < 4; ++j)
                    obase[(size_t)(row0 + j) * D_EMB + cl] =
                        __expf(0.5f * (acc[m][ns][j] + bvs));
            }
        }
    }

    // ================= phase 2: mu, pure compute =================
#pragma unroll
    for (int m = 0; m < 4; ++m)
#pragma unroll
        for (int n = 0; n < 4; ++n)
            acc[m][n] = (f32x4){0.f, 0.f, 0.f, 0.f};

#pragma unroll
    for (int tt = 0; tt < NT; tt += 4) {
        TILE_BODY(tt,     e0p1, bv0)
        TILE_BODY(tt + 1, e0p1, bv1)
        TILE_BODY(tt + 2, e0p1, bv2)
        TILE_BODY(tt + 3, e0p1, bv3)
    }
#undef TILE_BODY

    {
        float* __restrict__ obase = out;              // mu (cheap tail)
#pragma unroll
        for (int m = 0; m < 4; ++m) {
            const int row0 = bm * 64 + m * 16 + g16 * 4;
#pragma unroll
            for (int ns = 0; ns < 4; ++ns) {
                const int cl = wc * 64 + ns * 16 + fr;
                const float bvs = b_mu[cl];
#pragma unroll
                for (int j = 0; j < 4; ++j)
                    obase[(size_t)(row0 + j) * D_EMB + cl] = acc[m][ns][j] + bvs;
            }
        }
    }
}

// ============================================================
// Fallback (no workspace): round-1 f32-staging GEMM
// ============================================================
#define LDS_STRIDE 40
__global__ __launch_bounds__(256) void gpe_gemm_fb(
    const float* __restrict__ x, const float* __restrict__ W_mu,
    const float* __restrict__ b_mu, const float* __restrict__ W_logvar,
    const float* __restrict__ b_logvar, float* __restrict__ out)
{
    __shared__ __align__(16) bf16 As[128][LDS_STRIDE];
    __shared__ __align__(16) bf16 Bs[128][LDS_STRIDE];
    const int tid = threadIdx.x, lane = tid & 63, wid = tid >> 6;
    const int wr = wid >> 1, wcn = wid & 1;
    const int bn = blockIdx.x & 7, bm = blockIdx.x >> 3;
    const int ebase = bn * 128;
    const bool is_mu = (ebase < D_EMB);
    const float* Wp = is_mu ? (W_mu + (size_t)ebase * K_TOT)
                            : (W_logvar + (size_t)(ebase - D_EMB) * K_TOT);
    const float* bias = is_mu ? b_mu : b_logvar;
    const int cbase = is_mu ? ebase : (ebase - D_EMB);
    float* obase = is_mu ? out : (out + (size_t)M_TOT * D_EMB);
    const float* Ap = x + (size_t)(bm * 128) * K_TOT;
    f32x4 acc[4][4];
#pragma unroll
    for (int m = 0; m < 4; ++m)
#pragma unroll
        for (int n = 0; n < 4; ++n) acc[m][n] = (f32x4){0.f, 0.f, 0.f, 0.f};
    const int fr = lane & 15, fk = (lane >> 4) * 8;
    const int arow = wr * 64 + fr, brow = wcn * 64 + fr;
    for (int kt = 0; kt < K_TOT / 32; ++kt) {
        const int k0 = kt * 32;
#pragma unroll
        for (int s = 0; s < 4; ++s) {
            const int idx = s * 256 + tid;
            const int row = idx >> 3, col = (idx & 7) << 2;
            f32x4 va = *reinterpret_cast<const f32x4*>(Ap + (size_t)row * K_TOT + k0 + col);
            f32x4 vb = *reinterpret_cast<const f32x4*>(Wp + (size_t)row * K_TOT + k0 + col);
            bf16x4 ha, hb;
#pragma unroll
            for (int j = 0; j < 4; ++j) { ha[j] = (bf16)va[j]; hb[j] = (bf16)vb[j]; }
            *reinterpret_cast<bf16x4*>(&As[row][col]) = ha;
            *reinterpret_cast<bf16x4*>(&Bs[row][col]) = hb;
        }
        __syncthreads();
        bf16x8 af[4], bfv[4];
#pragma unroll
        for (int m = 0; m < 4; ++m)
            af[m] = *reinterpret_cast<const bf16x8*>(&As[arow + m * 16][fk]);
#pragma unroll
        for (int n = 0; n < 4; ++n)
            bfv[n] = *reinterpret_cast<const bf16x8*>(&Bs[brow + n * 16][fk]);
#pragma unroll
        for (int m = 0; m < 4; ++m)
#pragma unroll
            for (int n = 0; n < 4; ++n)
                acc[m][n] = __builtin_amdgcn_mfma_f32_16x16x32_bf16(af[m], bfv[n], acc[m][n], 0, 0, 0);
        __syncthreads();
    }
#pragma unroll
    for (int m = 0; m < 4; ++m) {
        const int rbase = bm * 128 + wr * 64 + m * 16 + (lane >> 4) * 4;
#pragma unroll
        for (int n = 0; n < 4; ++n) {
            const int c = cbase + wcn * 64 + n * 16 + (lane & 15);
            const float bv = bias[c];
#pragma unroll
            for (int j = 0; j < 4; ++j) {
                float v = acc[m][n][j] + bv;
                if (!is_mu) v = __expf(0.5f * v);
                obase[(size_t)(rbase + j) * D_EMB + c] = v;
            }
        }
    }
}

extern "C" void kernel_launch(void* const* d_in, const int* in_sizes, int n_in,
                              void* d_out, int out_size, void* d_ws, size_t ws_size,
                              hipStream_t stream) {
    const float* x        = (const float*)d_in[0];
    const float* W_mu     = (const float*)d_in[1];
    const float* b_mu     = (const float*)d_in[2];
    const float* W_logvar = (const float*)d_in[3];
    const float* b_logvar = (const float*)d_in[4];
    float* out = (float*)d_out;

    const size_t ws_needed = (size_t)1024 * 1024 * sizeof(bf16);   // 2 MB W image

    if (ws_size >= ws_needed) {
        bf16* wimg = (bf16*)d_ws;
        cvt_w_img<<<512, 256, 0, stream>>>(W_mu, W_logvar, wimg);
        gpe_tall5<<<256, 512, 0, stream>>>(x, wimg, b_mu, b_logvar, out);
    } else {
        gpe_gemm_fb<<<1024, 256, 0, stream>>>(x, W_mu, b_mu, W_logvar, b_logvar, out);
    }
}

// Round 17
// 48.264 us; speedup vs baseline: 1.6750x; 1.2006x over previous
//
#include <hip/hip_runtime.h>
#include <hip/hip_bf16.h>
#include <math.h>

typedef __bf16 bf16;
typedef __attribute__((ext_vector_type(4))) float f32x4;
typedef __attribute__((ext_vector_type(4))) bf16 bf16x4;
typedef __attribute__((ext_vector_type(8))) bf16 bf16x8;

#define M_TOT 16384
#define K_TOT 1024
#define D_EMB 512
#define NT 32          // K tiles of 32

// ============================================================
// Pass 0 (verified r9-r16): W -> fragment-ordered bf16 image (2 MB).
// Blob (es, kt) = 1 KB:
//   img[es*16384 + kt*512 + l*8 + j]
//     = W_cat[es*16 + (l&15)][kt*32 + (l>>4)*8 + j]
// ============================================================
__global__ __launch_bounds__(256) void cvt_w_img(
    const float* __restrict__ W_mu, const float* __restrict__ W_logvar,
    bf16* __restrict__ img)
{
    const int c  = blockIdx.x * 256 + threadIdx.x;   // 0..131071
    const int l  = c & 63;
    const int kt = (c >> 6) & 31;
    const int es = c >> 11;                          // 0..63
    const int col = es * 16 + (l & 15);
    const int k0  = kt * 32 + (l >> 4) * 8;
    const float* s = (col < D_EMB) ? (W_mu + (size_t)col * K_TOT + k0)
                                   : (W_logvar + (size_t)(col - D_EMB) * K_TOT + k0);
    f32x4 a = ((const f32x4*)s)[0];
    f32x4 b = ((const f32x4*)s)[1];
    bf16x8 o;
    o[0] = (bf16)a[0]; o[1] = (bf16)a[1]; o[2] = (bf16)a[2]; o[3] = (bf16)a[3];
    o[4] = (bf16)b[0]; o[5] = (bf16)b[1]; o[6] = (bf16)b[2]; o[7] = (bf16)b[3];
    *(bf16x8*)(img + (size_t)c * 8) = o;
}

// ============================================================
// EXACT r14 kernel (measured 48.57 us total, no spill at 128 VGPR).
// Tall-skinny, whole-K-in-LDS, kernel-scale pipelined.
// Block = 64 rows x 1024 cols, grid 256 (x read exactly once).
// 8 waves; per phase each wave owns 64 rows x 64 cols (acc[4][4]).
//   Phase 1 (mu): K-loop with CHUNKED staging — 4 chunks of 8 tiles;
//     gload(c+1) in flight during chunk-c compute; vmcnt(8) per chunk
//     (counted: leaves 2-deep B prefetch alive); one barrier per chunk.
//     Then store mu (33 MB, fire-and-forget).
//   Phase 2 (logvar): K-loop over the SAME resident LDS, zero
//     barriers, zero staging; mu stores drain underneath. Store lv.
//   B: global->VGPR 2-tile ping-pong from fragment image (L2-res).
// FIFO ledger/chunk c>0: outstanding at vmcnt(8) = gload(c):8 oldest
// + B(next2):8 youngest -> vmcnt(8) drains exactly gload(c). c=0:
// vmcnt(0). lgkm(0)+barrier per chunk = visibility; chunk regions
// write-disjoint -> no WAR. B waits compiler-counted off reg deps.
// ============================================================
__global__ __launch_bounds__(512, 1) void gpe_tall3(
    const float* __restrict__ x,
    const bf16* __restrict__ wimg,
    const float* __restrict__ b_mu,
    const float* __restrict__ b_logvar,
    float* __restrict__ out)         // [2][16384][512]
{
    __shared__ __align__(16) bf16 Alds[64 * 1024];   // 128 KB

    const int tid  = threadIdx.x;
    const int lane = tid & 63;
    const int wc   = tid >> 6;        // 0..7 : 64-col band within phase half
    const int fr   = lane & 15;
    const int g16  = lane >> 4;       // 0..3
    const int frx  = fr & 7;          // read-swizzle XOR
    const int bm   = blockIdx.x;      // 0..255 : 64-row slice

    // ---- staging geometry (verified r13/r14) ----
    const int arow = tid >> 3;                        // 0..63
    const int sl0  = tid & 7;
    const int rx   = arow & 7;
    const float* __restrict__ Asrc = x + (size_t)(bm * 64 + arow) * K_TOT;

    f32x4 stg[8];
    auto gload = [&](int c) {
#pragma unroll
        for (int j = 0; j < 4; ++j) {
            const int s = c * 32 + sl0 + 8 * j;
            stg[2 * j]     = *(const f32x4*)(Asrc + s * 8);
            stg[2 * j + 1] = *(const f32x4*)(Asrc + s * 8 + 4);
        }
    };
    auto cvtwrite = [&](int c) {
#pragma unroll
        for (int j = 0; j < 4; ++j) {
            const int s = c * 32 + sl0 + 8 * j;
            bf16x8 w;
#pragma unroll
            for (int q = 0; q < 4; ++q) {
                w[q]     = (bf16)stg[2 * j][q];
                w[q + 4] = (bf16)stg[2 * j + 1][q];
            }
            *(bf16x8*)&Alds[arow * 1024 + (s ^ rx) * 8] = w;
        }
    };

    // ---- B: 4 estrips per wave per phase ----
    const bf16* __restrict__ bl = wimg + lane * 8;
    bf16x8 bvA[4], bvB[4];
    auto loadB = [&](size_t e0, int t, bf16x8 (&bv)[4]) {
#pragma unroll
        for (int ns = 0; ns < 4; ++ns)
            bv[ns] = *(const bf16x8*)(bl + e0 + (size_t)ns * 16384 + t * 512);
    };

    f32x4 acc[4][4];
#pragma unroll
    for (int m = 0; m < 4; ++m)
#pragma unroll
        for (int n = 0; n < 4; ++n)
            acc[m][n] = (f32x4){0.f, 0.f, 0.f, 0.f};

    const size_t e0p0 = (size_t)(wc * 4) * 16384;        // phase-1 estrip base (mu)
    const size_t e0p1 = (size_t)(32 + wc * 4) * 16384;   // phase-2 (logvar)

#define TILE_BODY(T, E0, BVC)                                                  \
    {                                                                          \
        const int t = (T);                                                     \
        bf16x8 afc[4];                                                         \
        _Pragma("unroll")                                                      \
        for (int m = 0; m < 4; ++m)                                            \
            afc[m] = *(const bf16x8*)&Alds[(m * 16 + fr) * 1024                \
                                           + ((t * 4 + g16) ^ frx) * 8];       \
        __builtin_amdgcn_s_setprio(1);                                         \
        _Pragma("unroll")                                                      \
        for (int ns = 0; ns < 4; ++ns)                                         \
            _Pragma("unroll")                                                  \
            for (int m = 0; m < 4; ++m)                                        \
                acc[m][ns] = __builtin_amdgcn_mfma_f32_16x16x32_bf16(          \
                    afc[m], BVC[ns], acc[m][ns], 0, 0, 0);                     \
        __builtin_amdgcn_s_setprio(0);                                         \
        if (t + 2 < NT) loadB(E0, t + 2, BVC);                                 \
    }

    // ================= phase 1: mu + chunked staging =================
    gload(0);
    for (int c = 0; c < 4; ++c) {
        if (c == 0) asm volatile("s_waitcnt vmcnt(0)" ::: "memory");
        else        asm volatile("s_waitcnt vmcnt(8)" ::: "memory");
        cvtwrite(c);
        if (c < 3) gload(c + 1);
        if (c == 0) { loadB(e0p0, 0, bvA); loadB(e0p0, 1, bvB); }
        asm volatile("s_waitcnt lgkmcnt(0)" ::: "memory");
        __builtin_amdgcn_s_barrier();
#pragma unroll
        for (int tt = 0; tt < 8; tt += 2) {
            TILE_BODY(c * 8 + tt,     e0p0, bvA)
            TILE_BODY(c * 8 + tt + 1, e0p0, bvB)
        }
    }

    // phase-2 B prologue first (loads), then mu stores (drain in background)
    loadB(e0p1, 0, bvA);
    loadB(e0p1, 1, bvB);
    {
        float* __restrict__ obase = out;              // mu half
#pragma unroll
        for (int m = 0; m < 4; ++m) {
            const int row0 = bm * 64 + m * 16 + g16 * 4;
#pragma unroll
            for (int ns = 0; ns < 4; ++ns) {
                const int cl = wc * 64 + ns * 16 + fr;
                const float bvs = b_mu[cl];
#pragma unroll
                for (int j = 0; j < 4; ++j)
                    obase[(size_t)(row0 + j) * D_EMB + cl] = acc[m][ns][j] + bvs;
            }
        }
    }

    // ================= phase 2: logvar, pure compute =================
#pragma unroll
    for (int m = 0; m < 4; ++m)
#pragma unroll
        for (int n = 0; n < 4; ++n)
            acc[m][n] = (f32x4){0.f, 0.f, 0.f, 0.f};

#pragma unroll
    for (int tt = 0; tt < NT; tt += 2) {
        TILE_BODY(tt,     e0p1, bvA)
        TILE_BODY(tt + 1, e0p1, bvB)
    }
#undef TILE_BODY

    {
        float* __restrict__ obase = out + (size_t)M_TOT * D_EMB;   // logvar half
#pragma unroll
        for (int m = 0; m < 4; ++m) {
            const int row0 = bm * 64 + m * 16 + g16 * 4;
#pragma unroll
            for (int ns = 0; ns < 4; ++ns) {
                const int cl = wc * 64 + ns * 16 + fr;
                const float bvs = b_logvar[cl];
#pragma unroll
                for (int j = 0; j < 4; ++j)
                    obase[(size_t)(row0 + j) * D_EMB + cl] =
                        __expf(0.5f * (acc[m][ns][j] + bvs));
            }
        }
    }
}

// ============================================================
// Fallback (no workspace): round-1 f32-staging GEMM
// ============================================================
#define LDS_STRIDE 40
__global__ __launch_bounds__(256) void gpe_gemm_fb(
    const float* __restrict__ x, const float* __restrict__ W_mu,
    const float* __restrict__ b_mu, const float* __restrict__ W_logvar,
    const float* __restrict__ b_logvar, float* __restrict__ out)
{
    __shared__ __align__(16) bf16 As[128][LDS_STRIDE];
    __shared__ __align__(16) bf16 Bs[128][LDS_STRIDE];
    const int tid = threadIdx.x, lane = tid & 63, wid = tid >> 6;
    const int wr = wid >> 1, wcn = wid & 1;
    const int bn = blockIdx.x & 7, bm = blockIdx.x >> 3;
    const int ebase = bn * 128;
    const bool is_mu = (ebase < D_EMB);
    const float* Wp = is_mu ? (W_mu + (size_t)ebase * K_TOT)
                            : (W_logvar + (size_t)(ebase - D_EMB) * K_TOT);
    const float* bias = is_mu ? b_mu : b_logvar;
    const int cbase = is_mu ? ebase : (ebase - D_EMB);
    float* obase = is_mu ? out : (out + (size_t)M_TOT * D_EMB);
    const float* Ap = x + (size_t)(bm * 128) * K_TOT;
    f32x4 acc[4][4];
#pragma unroll
    for (int m = 0; m < 4; ++m)
#pragma unroll
        for (int n = 0; n < 4; ++n) acc[m][n] = (f32x4){0.f, 0.f, 0.f, 0.f};
    const int fr = lane & 15, fk = (lane >> 4) * 8;
    const int arow = wr * 64 + fr, brow = wcn * 64 + fr;
    for (int kt = 0; kt < K_TOT / 32; ++kt) {
        const int k0 = kt * 32;
#pragma unroll
        for (int s = 0; s < 4; ++s) {
            const int idx = s * 256 + tid;
            const int row = idx >> 3, col = (idx & 7) << 2;
            f32x4 va = *reinterpret_cast<const f32x4*>(Ap + (size_t)row * K_TOT + k0 + col);
            f32x4 vb = *reinterpret_cast<const f32x4*>(Wp + (size_t)row * K_TOT + k0 + col);
            bf16x4 ha, hb;
#pragma unroll
            for (int j = 0; j < 4; ++j) { ha[j] = (bf16)va[j]; hb[j] = (bf16)vb[j]; }
            *reinterpret_cast<bf16x4*>(&As[row][col]) = ha;
            *reinterpret_cast<bf16x4*>(&Bs[row][col]) = hb;
        }
        __syncthreads();
        bf16x8 af[4], bfv[4];
#pragma unroll
        for (int m = 0; m < 4; ++m)
            af[m] = *reinterpret_cast<const bf16x8*>(&As[arow + m * 16][fk]);
#pragma unroll
        for (int n = 0; n < 4; ++n)
            bfv[n] = *reinterpret_cast<const bf16x8*>(&Bs[brow + n * 16][fk]);
#pragma unroll
        for (int m = 0; m < 4; ++m)
#pragma unroll
            for (int n = 0; n < 4; ++n)
                acc[m][n] = __builtin_amdgcn_mfma_f32_16x16x32_bf16(af[m], bfv[n], acc[m][n], 0, 0, 0);
        __syncthreads();
    }
#pragma unroll
    for (int m = 0; m < 4; ++m) {
        const int rbase = bm * 128 + wr * 64 + m * 16 + (lane >> 4) * 4;
#pragma unroll
        for (int n = 0; n < 4; ++n) {
            const int c = cbase + wcn * 64 + n * 16 + (lane & 15);
            const float bv = bias[c];
#pragma unroll
            for (int j = 0; j < 4; ++j) {
                float v = acc[m][n][j] + bv;
                if (!is_mu) v = __expf(0.5f * v);
                obase[(size_t)(rbase + j) * D_EMB + c] = v;
            }
        }
    }
}

extern "C" void kernel_launch(void* const* d_in, const int* in_sizes, int n_in,
                              void* d_out, int out_size, void* d_ws, size_t ws_size,
                              hipStream_t stream) {
    const float* x        = (const float*)d_in[0];
    const float* W_mu     = (const float*)d_in[1];
    const float* b_mu     = (const float*)d_in[2];
    const float* W_logvar = (const float*)d_in[3];
    const float* b_logvar = (const float*)d_in[4];
    float* out = (float*)d_out;

    const size_t ws_needed = (size_t)1024 * 1024 * sizeof(bf16);   // 2 MB W image

    if (ws_size >= ws_needed) {
        bf16* wimg = (bf16*)d_ws;
        cvt_w_img<<<512, 256, 0, stream>>>(W_mu, W_logvar, wimg);
        gpe_tall3<<<256, 512, 0, stream>>>(x, wimg, b_mu, b_logvar, out);
    } else {
        gpe_gemm_fb<<<1024, 256, 0, stream>>>(x, W_mu, b_mu, W_logvar, b_logvar, out);
    }
}